// Round 9
// baseline (62.087 us; speedup 1.0000x reference)
//
#include <hip/hip_runtime.h>
#include <hip/hip_bf16.h>

// Fused shift/roll/unfold/conv (all f32):
//   r[h,k,o,l] = gate_b(k,o)*x[l,h,widx_b(k,o)] + gate_a(k,o)*x[128+l,h,widx_a(k,o)]
//   y[i,n,o]   = sum_{j,k,l} r[n+j-1,k,o,l] * w[i,j,k,l]
//
// Grid (14 n, 2 os, 16 ig) = 448 blocks, block 256 (4 waves) -> 2 blocks/CU (LDS 32 KB).
// Wave wv owns i = ig*16 + wv*4 + (0..3); block covers o = os*7 + (0..6).
// Phase 1: thread items (j=t>>7,l=t&127) and (t<128: j=2,l=t): x rows -> regs ->
//          21 static-index r values (template<OS> keeps reg indices compile-time) -> rs.
// Phase 2: q-split per lane (q = qi*256+lane*4, tail 1024+lane*2); 4 i per lane;
//          DPP 64-lane reduction -> lane 63 stores. One barrier; two blocks/CU overlap drains.

template<int CTRL, int RM>
__device__ __forceinline__ float dpp_add(float v) {
    int moved = __builtin_amdgcn_update_dpp(0, __float_as_int(v), CTRL, RM, 0xf, true);
    return v + __int_as_float(moved);
}

// Canonical 64-lane sum; result valid in lane 63.
__device__ __forceinline__ float wave_sum64(float v) {
    v = dpp_add<0x111, 0xf>(v);   // row_shr:1
    v = dpp_add<0x112, 0xf>(v);   // row_shr:2
    v = dpp_add<0x114, 0xf>(v);   // row_shr:4
    v = dpp_add<0x118, 0xf>(v);   // row_shr:8
    v = dpp_add<0x142, 0xa>(v);   // row_bcast:15
    v = dpp_add<0x143, 0xc>(v);   // row_bcast:31 -> lane63 = total
    return v;
}

// Build r rows for one (j,l) into rs[(j*3+k)*7+oo][l]; OS template => compile-time reg idx.
template<int OS>
__device__ __forceinline__ void build_r(const float* __restrict__ x,
                                        float* __restrict__ rs,
                                        int n, int j, int l) {
    const int h = n + j - 1;
    float xlo[14], xhi[14];
    if ((unsigned)h < 14u) {                    // wave-uniform branch
        const float* p0 = x + l * 196 + h * 14;
        const float* p1 = x + (128 + l) * 196 + h * 14;
        #pragma unroll
        for (int wi = 0; wi < 14; wi += 2) {
            float2 a = *(const float2*)(p0 + wi);
            float2 b = *(const float2*)(p1 + wi);
            xlo[wi] = a.x; xlo[wi + 1] = a.y;
            xhi[wi] = b.x; xhi[wi + 1] = b.y;
        }
    } else {
        #pragma unroll
        for (int wi = 0; wi < 14; ++wi) { xlo[wi] = 0.f; xhi[wi] = 0.f; }
    }
    #pragma unroll
    for (int k = 0; k < 3; ++k) {
        #pragma unroll
        for (int oo = 0; oo < 7; ++oo) {
            const int o = OS * 7 + oo;                // compile-time
            float val = 0.f;
            const int wb = o + k - 1;                 // B-term gate/index
            if (wb >= 0 && wb < 14) val += xlo[wb ? wb - 1 : 13];
            const int v  = o ? o - 1 : 13;            // A-term gate/index
            const int wa = v + k - 1;
            if (wa >= 0 && wa < 14) val += xhi[wa ? wa - 1 : 13];
            rs[((j * 3 + k) * 7 + oo) * 128 + l] = val;
        }
    }
}

__global__ __launch_bounds__(256) void fused_shiftconv(
    const float* __restrict__ x,    // (256,14,14)
    const float* __restrict__ w,    // (256,3,3,128): i*1152 + (j*3+k)*128 + l
    float* __restrict__ out)        // (256,14,14)
{
    __shared__ __align__(16) float rs[63 * 128];   // 32256 B -> 2 blocks/CU

    const int n    = blockIdx.x;
    const int os   = blockIdx.y;          // 0/1: o-half
    const int ig   = blockIdx.z;          // 0..15: 16 i per block
    const int t    = threadIdx.x;
    const int lane = t & 63;
    const int wv   = t >> 6;              // 0..3

    // ---- w staging into registers: 4 i per wave, 18 q per lane (72 floats) ----
    const int ibase = ig * 16 + wv * 4;
    float4 wq[4][4];
    float2 wt[4];
    #pragma unroll
    for (int ii = 0; ii < 4; ++ii) {
        const float* wp = w + (ibase + ii) * 1152;
        #pragma unroll
        for (int qi = 0; qi < 4; ++qi)
            wq[ii][qi] = *(const float4*)(wp + qi * 256 + lane * 4);
        wt[ii] = *(const float2*)(wp + 1024 + lane * 2);
    }

    // ---- Phase 1: build this block's 7-o slice of r ----
    {
        const int j0 = t >> 7;            // 0 or 1
        const int l0 = t & 127;
        if (os == 0) {
            build_r<0>(x, rs, n, j0, l0);
            if (t < 128) build_r<0>(x, rs, n, 2, t);
        } else {
            build_r<1>(x, rs, n, j0, l0);
            if (t < 128) build_r<1>(x, rs, n, 2, t);
        }
    }
    __syncthreads();   // the only barrier; 2 blocks/CU overlap the drain

    // ---- Phase 2: 7 o's; per o: 5 LDS reads, 4 i dots, DPP reduce, lane-63 store ----
    const int rbl  = (lane & 31) * 4;     // l base for qi chunks
    const int jkhi = lane >> 5;           // 0/1: jk = qi*2 + jkhi
    #pragma unroll
    for (int oo = 0; oo < 7; ++oo) {
        const float* rb = rs + oo * 128 + rbl;          // row stride jk: 7*128 = 896
        float4 rv0 = *(const float4*)(rb + (0 + jkhi) * 896);
        float4 rv1 = *(const float4*)(rb + (2 + jkhi) * 896);
        float4 rv2 = *(const float4*)(rb + (4 + jkhi) * 896);
        float4 rv3 = *(const float4*)(rb + (6 + jkhi) * 896);
        float2 rt  = *(const float2*)(rs + (56 + oo) * 128 + lane * 2);
        float s[4];
        #pragma unroll
        for (int ii = 0; ii < 4; ++ii) {
            float a0, a1;
            a0  = rv0.x * wq[ii][0].x + rv0.y * wq[ii][0].y + rv0.z * wq[ii][0].z + rv0.w * wq[ii][0].w;
            a1  = rv1.x * wq[ii][1].x + rv1.y * wq[ii][1].y + rv1.z * wq[ii][1].z + rv1.w * wq[ii][1].w;
            a0 += rv2.x * wq[ii][2].x + rv2.y * wq[ii][2].y + rv2.z * wq[ii][2].z + rv2.w * wq[ii][2].w;
            a1 += rv3.x * wq[ii][3].x + rv3.y * wq[ii][3].y + rv3.z * wq[ii][3].z + rv3.w * wq[ii][3].w;
            a0 += rt.x * wt[ii].x + rt.y * wt[ii].y;
            s[ii] = wave_sum64(a0 + a1);
        }
        if (lane == 63) {
            const int o = os * 7 + oo;
            #pragma unroll
            for (int ii = 0; ii < 4; ++ii)
                out[(ibase + ii) * 196 + n * 14 + o] = s[ii];
        }
    }
}

extern "C" void kernel_launch(void* const* d_in, const int* in_sizes, int n_in,
                              void* d_out, int out_size, void* d_ws, size_t ws_size,
                              hipStream_t stream) {
    const float* x = (const float*)d_in[0];  // 256*14*14
    const float* w = (const float*)d_in[1];  // 256*3*3*128
    float* out = (float*)d_out;              // 256*14*14
    dim3 grid(14, 2, 16);
    fused_shiftconv<<<grid, 256, 0, stream>>>(x, w, out);
}

// Round 10
// 60.763 us; speedup vs baseline: 1.0218x; 1.0218x over previous
//
#include <hip/hip_runtime.h>
#include <hip/hip_bf16.h>

// Fused shift/roll/unfold/conv (all f32, f32 LDS intermediates):
//   r[h,k,o,l] = gate_b(k,o)*x[l,h,widx_b(k,o)] + gate_a(k,o)*x[128+l,h,widx_a(k,o)]
//   y[i,n,o]   = sum_{j,k,l} r[n+j-1,k,o,l] * w[i,j,k,l]
//
// FINAL (R7 lock-in, measured best 60.65 us / absmax 0.5).
// Grid (14 n, 16 ig) = 224 blocks (single round). Block 512 (8 waves), 16 i/block, 2 i/wave.
// Phase 1 (384 thr): thread=(j,l): x rows (global, L2-resident) -> regs -> 42 static r -> rs f32.
// Phase 2: q-split across lanes (q = qi*256+lane*4, tail 1024+lane*2); w in registers.
//          parts row stride 64 with 4-float rotation p=(e+4*row)&63 -> conflict-min both ways.
// Phase 3 (224 thr = 224 outputs): float4 reduce at minimum 8 words/bank.
//
// Session ledger (bench dur_us): R5 61.0 (8-wave LDS partials) | R6 67.3 (staged xs: extra
// barrier serialization regressed) | R7 60.65 (this) | R8 61.7 (DPP 1-barrier) | R9 62.1
// (2 blocks/CU). Plateau: harness fill 40us @84% HBM + ~10us restores/graph + ~5-9us kernel.

#define PSTR 64

__global__ __launch_bounds__(512) void fused_shiftconv(
    const float* __restrict__ x,    // (256,14,14)
    const float* __restrict__ w,    // (256,3,3,128): i*1152 + (j*3+k)*128 + l
    float* __restrict__ out)        // (256,14,14)
{
    __shared__ __align__(16) float rs[126 * 128];      // 64512 B f32 r-slice
    __shared__ __align__(16) float parts[224 * PSTR];  // 57344 B rotated lane-partials

    const int n    = blockIdx.x;
    const int ig   = blockIdx.y;          // 0..15, 16 i per block
    const int t    = threadIdx.x;
    const int lane = t & 63;
    const int wv   = t >> 6;              // 0..7

    // ---- w staging into registers (coalesced, overlaps phase 1) ----
    const float* wbase = w + (ig * 16 + wv * 2) * 1152;
    float4 wq[2][4];
    float2 wt[2];
    #pragma unroll
    for (int ii = 0; ii < 2; ++ii) {
        const float* wp = wbase + ii * 1152;
        #pragma unroll
        for (int qi = 0; qi < 4; ++qi)
            wq[ii][qi] = *(const float4*)(wp + qi * 256 + lane * 4);
        wt[ii] = *(const float2*)(wp + 1024 + lane * 2);
    }

    // ---- Phase 1: build rs (384 threads; thread = (j = t>>7, l = t&127)) ----
    if (t < 384) {
        const int j = t >> 7;
        const int l = t & 127;
        const int h = n + j - 1;
        float xlo[14], xhi[14];
        if ((unsigned)h < 14u) {                    // wave-uniform branch
            const float* p0 = x + l * 196 + h * 14;
            const float* p1 = x + (128 + l) * 196 + h * 14;
            #pragma unroll
            for (int wi = 0; wi < 14; wi += 2) {
                float2 a = *(const float2*)(p0 + wi);
                float2 b = *(const float2*)(p1 + wi);
                xlo[wi] = a.x; xlo[wi + 1] = a.y;
                xhi[wi] = b.x; xhi[wi + 1] = b.y;
            }
        } else {
            #pragma unroll
            for (int wi = 0; wi < 14; ++wi) { xlo[wi] = 0.f; xhi[wi] = 0.f; }
        }
        // 42 (k,o) values, all indices compile-time after unroll
        #pragma unroll
        for (int k = 0; k < 3; ++k) {
            #pragma unroll
            for (int o = 0; o < 14; ++o) {
                float val = 0.f;
                const int wb = o + k - 1;                 // B-term gate/index
                if (wb >= 0 && wb < 14) val += xlo[wb ? wb - 1 : 13];
                const int v  = o ? o - 1 : 13;            // A-term gate/index
                const int wa = v + k - 1;
                if (wa >= 0 && wa < 14) val += xhi[wa ? wa - 1 : 13];
                rs[((j * 3 + k) * 14 + o) * 128 + l] = val;
            }
        }
    }
    __syncthreads();

    // ---- Phase 2: per o, per-lane partial dots (18 q per lane, 2 i per wave) ----
    const int rbl   = (lane & 31) * 4;     // l base for qi chunks
    const int jkhi  = lane >> 5;           // 0/1: jk = qi*2 + jkhi
    const int prow0 = wv * 28;             // partial row base
    #pragma unroll 2
    for (int o = 0; o < 14; ++o) {
        const int ro = o * 128;
        float4 rv0 = *(const float4*)(rs + ((0 * 2 + jkhi) * 14) * 128 + ro + rbl);
        float4 rv1 = *(const float4*)(rs + ((1 * 2 + jkhi) * 14) * 128 + ro + rbl);
        float4 rv2 = *(const float4*)(rs + ((2 * 2 + jkhi) * 14) * 128 + ro + rbl);
        float4 rv3 = *(const float4*)(rs + ((3 * 2 + jkhi) * 14) * 128 + ro + rbl);
        float2 rt  = *(const float2*)(rs + (112 + o) * 128 + lane * 2);
        #pragma unroll
        for (int ii = 0; ii < 2; ++ii) {
            float a0, a1;
            a0  = rv0.x * wq[ii][0].x + rv0.y * wq[ii][0].y + rv0.z * wq[ii][0].z + rv0.w * wq[ii][0].w;
            a1  = rv1.x * wq[ii][1].x + rv1.y * wq[ii][1].y + rv1.z * wq[ii][1].z + rv1.w * wq[ii][1].w;
            a0 += rv2.x * wq[ii][2].x + rv2.y * wq[ii][2].y + rv2.z * wq[ii][2].z + rv2.w * wq[ii][2].w;
            a1 += rv3.x * wq[ii][3].x + rv3.y * wq[ii][3].y + rv3.z * wq[ii][3].z + rv3.w * wq[ii][3].w;
            a0 += rt.x * wt[ii].x + rt.y * wt[ii].y;
            const int row = prow0 + ii * 14 + o;
            parts[row * PSTR + ((lane + 4 * row) & 63)] = a0 + a1;   // rotated: conflict-free
        }
    }
    __syncthreads();

    // ---- Phase 3: reduce 64 rotated lane-partials per output (224 thr = 224 outputs) ----
    if (t < 224) {
        const float* pr = parts + t * PSTR;
        float s0 = 0.f, s1 = 0.f;
        #pragma unroll
        for (int g = 0; g < 16; g += 2) {
            float4 v0 = *(const float4*)(pr + ((4 * g + 4 * t) & 63));        // min 8 words/bank
            float4 v1 = *(const float4*)(pr + ((4 * (g + 1) + 4 * t) & 63));
            s0 += v0.x + v0.y + v0.z + v0.w;
            s1 += v1.x + v1.y + v1.z + v1.w;
        }
        const int wv2 = t / 28;
        const int rem = t - wv2 * 28;
        const int ii  = rem / 14;
        const int o   = rem - ii * 14;
        const int i   = ig * 16 + wv2 * 2 + ii;
        out[(i * 14 + n) * 14 + o] = s0 + s1;
    }
}

extern "C" void kernel_launch(void* const* d_in, const int* in_sizes, int n_in,
                              void* d_out, int out_size, void* d_ws, size_t ws_size,
                              hipStream_t stream) {
    const float* x = (const float*)d_in[0];  // 256*14*14
    const float* w = (const float*)d_in[1];  // 256*3*3*128
    float* out = (float*)d_out;              // 256*14*14
    dim3 grid(14, 16);
    fused_shiftconv<<<grid, 512, 0, stream>>>(x, w, out);
}